// Round 15
// baseline (2991.828 us; speedup 1.0000x reference)
//
#include <hip/hip_runtime.h>
#include <hip/hip_bf16.h>
#include <stdint.h>

#define T_SEQ 2048
#define DDIM 256
#define G3 768
#define NB 64
#define NQR 10

typedef _Float16 h2f __attribute__((ext_vector_type(2)));
typedef _Float16 f16x8 __attribute__((ext_vector_type(8)));
typedef float f32x4 __attribute__((ext_vector_type(4)));
typedef unsigned u32x4 __attribute__((ext_vector_type(4)));

__device__ __forceinline__ float fdot2u(unsigned a, unsigned b, float c) {
    return __builtin_amdgcn_fdot2(__builtin_bit_cast(h2f, a),
                                  __builtin_bit_cast(h2f, b), c, false);
}
__device__ __forceinline__ unsigned packf16(float a, float b) {
    auto p = __builtin_amdgcn_cvt_pkrtz(a, b);   // __fp16 ext_vector(2)
    return __builtin_bit_cast(unsigned, p);
}
__device__ __forceinline__ float unpk(unsigned u, int hi) {
    h2f p = __builtin_bit_cast(h2f, u);
    return hi ? (float)p[1] : (float)p[0];
}
__device__ __forceinline__ float sigmf(float x) { return 1.0f / (1.0f + __expf(-x)); }
__device__ __forceinline__ float tanhff(float x) {
    float ax = fabsf(x);
    float e = __expf(2.0f * ax);
    float t = 1.0f - 2.0f / (e + 1.0f);
    return copysignf(t, x);
}

// ---------------- prologue: span selection + wcol + bsum + combined bias -------
// bias_comb[g] = b_ih[g] + (g<512 ? b_hh[g] : 0)   (b_hh r,z folded into gi)
// biasp = packed f16 pairs of bias_comb (gi fallback rows t >= len)
__global__ __launch_bounds__(256) void k_prologue(
    const float* __restrict__ logits, const float* __restrict__ spans,
    const float* __restrict__ W_sal, const float* __restrict__ b_sal,
    const float* __restrict__ b_ih, const float* __restrict__ b_hh,
    int* __restrict__ meta, float* __restrict__ wcol, float* __restrict__ bsum,
    float* __restrict__ bias_comb, unsigned* __restrict__ biasp) {
    int tid = threadIdx.x;
    if (tid < NB) {
        int b = tid;
        float bestv = -1e30f; int best = 0;
        for (int q = 0; q < NQR; ++q) {
            float l0 = logits[(b * NQR + q) * 2 + 0];
            float l1 = logits[(b * NQR + q) * 2 + 1];
            float sc = sigmf(l0 - l1);   // monotone in softmax[...,0]
            if (sc > bestv) { bestv = sc; best = q; }
        }
        float cx = spans[(b * NQR + best) * 2 + 0];
        float w  = spans[(b * NQR + best) * 2 + 1];
        float x0 = (cx - 0.5f * w) * (float)(T_SEQ * 2);
        float x1 = (cx + 0.5f * w) * (float)(T_SEQ * 2);
        int se0 = (int)floorf(x0 * 0.5f);
        int se1 = (int)floorf(x1 * 0.5f);
        int start = min(max(se0, 0), T_SEQ - 1);
        int end_eff = min(se1, T_SEQ - 1);
        int len = end_eff - start + 1;
        if (len < 0) len = 0;
        meta[b] = start; meta[NB + b] = len;
    }
    float acc = 0.f;
    for (int e = 0; e < DDIM; ++e) acc += W_sal[e * DDIM + tid];
    wcol[tid] = acc;
    if (tid < 64) {
        float p = b_sal[tid] + b_sal[tid + 64] + b_sal[tid + 128] + b_sal[tid + 192];
        for (int off = 32; off; off >>= 1) p += __shfl_down(p, off, 64);
        if (tid == 0) *bsum = p;
    }
#pragma unroll
    for (int r = 0; r < 3; ++r) {
        int g = tid + r * 256;
        bias_comb[g] = b_ih[g] + (g < 512 ? b_hh[g] : 0.f);
    }
    __syncthreads();
#pragma unroll
    for (int r = 0; r < 2; ++r) {
        int p = tid + r * 256;
        if (p < 384) biasp[p] = packf16(bias_comb[2 * p], bias_comb[2 * p + 1]);
    }
}

// ---------------- prep: pack W_hh to u32x4 f16 quads (k_gru format) ----------
__global__ __launch_bounds__(256) void k_prep(
    const float* __restrict__ W_hh, unsigned* __restrict__ w4) {
    int g = blockIdx.x, k = threadIdx.x;
    if (k < 128) {  // k = pair index
        unsigned v = packf16(W_hh[g * DDIM + 2 * k], W_hh[g * DDIM + 2 * k + 1]);
        w4[((k >> 2) * G3 + g) * 4 + (k & 3)] = v;
    }
}

// ---------------- prepI: W_ih -> MFMA B-fragments (f16 packed) ----------------
__global__ __launch_bounds__(256) void k_prepI(
    const float* __restrict__ W_ih, unsigned* __restrict__ wfragI) {
    int u = blockIdx.x * 256 + threadIdx.x;     // 98304 total
    int jj = u & 3;
    int l  = (u >> 2) & 63;
    int kc = (u >> 8) & 7;
    int ct = u >> 11;
    int col = ct * 16 + (l & 15);
    int k = kc * 32 + ((l >> 4) << 3) + jj * 2;
    wfragI[u] = packf16(W_ih[col * DDIM + k], W_ih[col * DDIM + k + 1]);
}

// ---------------- gi GEMM (MFMA): gi2 = f16(sliced @ W_ih^T + bias_comb) ------
__global__ __launch_bounds__(512, 2) void k_gemm(
    const float* __restrict__ src_vid, const unsigned* __restrict__ wfragI,
    const float* __restrict__ bias_comb, const int* __restrict__ meta,
    unsigned* __restrict__ gi2, int t0, int tc, int TC) {
    int b = blockIdx.y;
    int len = meta[NB + b];
    int start = meta[b];
    int tbase = t0 + blockIdx.x * 256;
    int tend = t0 + tc; if (tend > len) tend = len;
    int tcap = tbase + 256; if (tend > tcap) tend = tcap;
    if (tbase >= tend) return;

    int tid = threadIdx.x, lane = tid & 63, w = tid >> 6;

    u32x4 bfr[6][8];
    const u32x4* wf = (const u32x4*)wfragI;
#pragma unroll
    for (int j = 0; j < 6; ++j)
#pragma unroll
        for (int kc = 0; kc < 8; ++kc)
            bfr[j][kc] = wf[((w * 6 + j) * 8 + kc) * 64 + lane];

    int row = lane & 15, kg = lane >> 4;
    float bv[6];
#pragma unroll
    for (int j = 0; j < 6; ++j) bv[j] = bias_comb[(w * 6 + j) * 16 + row];

    __shared__ unsigned As[2048];   // 16 rows x 128 pairs, swizzled
    int sr = tid >> 5, sx = tid & 31;

    for (int tch = tbase; tch < tend; tch += 16) {
        int tr = tch + sr;
        u32x4 pk = {0u, 0u, 0u, 0u};
        if (tr < len) {
            const float* sp = src_vid + ((size_t)b * T_SEQ + start + tr) * DDIM + sx * 8;
            float4 a0 = *(const float4*)sp;
            float4 a1 = *(const float4*)(sp + 4);
            pk[0] = packf16(a0.x, a0.y); pk[1] = packf16(a0.z, a0.w);
            pk[2] = packf16(a1.x, a1.y); pk[3] = packf16(a1.z, a1.w);
        }
        *(u32x4*)&As[sr * 128 + ((sx ^ sr) << 2)] = pk;
        __syncthreads();

        f32x4 d[6];
#pragma unroll
        for (int j = 0; j < 6; ++j) d[j] = (f32x4){bv[j], bv[j], bv[j], bv[j]};
#pragma unroll
        for (int kc = 0; kc < 8; ++kc) {
            u32x4 av = *(const u32x4*)&As[row * 128 + (((kc * 4 + kg) ^ row) << 2)];
            f16x8 af = __builtin_bit_cast(f16x8, av);
#pragma unroll
            for (int j = 0; j < 6; ++j)
                d[j] = __builtin_amdgcn_mfma_f32_16x16x32_f16(
                    af, __builtin_bit_cast(f16x8, bfr[j][kc]), d[j], 0, 0, 0);
        }

#pragma unroll
        for (int j = 0; j < 6; ++j) {
            int cflat = (w * 6 + j) * 16 + row;
            int gate = cflat >> 8;
            int pairi = (cflat & 255) >> 1;
#pragma unroll
            for (int reg = 0; reg < 4; ++reg) {
                int t = tch + kg * 4 + reg;
                float v = d[j][reg];
                float o = __shfl_xor(v, 1, 64);
                if (!(lane & 1) && t < tend)
                    gi2[((size_t)b * TC + (t - t0)) * 384 + gate * 128 + pairi] =
                        packf16(v, o);
            }
        }
        __syncthreads();
    }
}

// ---------------- GRU recurrence: 1024 thr, K-quarter, hard 128-reg budget ----
// 16 waves (4/SIMD -> 128-reg unified budget: no AGPR parking possible).
// Thread (c, kq): 3 gates of col c over K-quarter [kq*64, kq*64+64):
// 24 weight quads = 96 regs. h-quad reads fully wave-uniform (broadcast).
// kq1-3 export 3 partials each; kq0 (1 wave/SIMD) reduces + finalizes.
// b_hh(r,z) pre-folded into gi via bias_comb; only bhN remains.
__global__ void __launch_bounds__(1024) k_gru(
    const unsigned* __restrict__ gi2, const unsigned* __restrict__ w4,
    const unsigned* __restrict__ biasp, const float* __restrict__ b_hh,
    const int* __restrict__ meta, float* __restrict__ h_state,
    int t0, int t1, int TC) {
    int b = blockIdx.x, tid = threadIdx.x;
    int c = tid & 255, kq = tid >> 8;
    int len = meta[NB + b];

    // resident weights: 24 quads (8 q x 3 gates), coalesced 16B/lane
    u32x4 wq[8][3];
    const u32x4* w4v = (const u32x4*)w4;
#pragma unroll
    for (int q = 0; q < 8; ++q)
#pragma unroll
        for (int g = 0; g < 3; ++g)
            wq[q][g] = w4v[(size_t)(kq * 8 + q) * G3 + g * 256 + c];

    float bhN = b_hh[512 + c];

    __shared__ unsigned hl[128];     // packed f16 h (256 values)
    __shared__ float pl[9][256];     // kq1-3 partials
    __shared__ unsigned bias2[384];  // gi fallback pairs (t >= len)

    if (tid < 384) bias2[tid] = biasp[tid];

    float h = 0.f;
    if (kq == 0) {
        if (t0 != 0) h = h_state[b * DDIM + c];
        float hp = __shfl_xor(h, 1, 64);
        if (!(c & 1)) hl[c >> 1] = packf16(h, hp);
    }

    const unsigned* gb2 = gi2 + (size_t)b * TC * 384 + (c >> 1);
    int sel = c & 1;
    float gR = 0.f, gZ = 0.f, gN = 0.f;
    __syncthreads();   // hl + bias2 ready
    if (kq == 0 && t0 < t1) {
        if (t0 < len) {
            gR = unpk(gb2[0], sel); gZ = unpk(gb2[128], sel); gN = unpk(gb2[256], sel);
        } else {
            gR = unpk(bias2[c >> 1], sel);
            gZ = unpk(bias2[128 + (c >> 1)], sel);
            gN = unpk(bias2[256 + (c >> 1)], sel);
        }
    }

    for (int t = t0; t < t1; ++t) {
        // prefetch next-step gi (kq0 only; hidden under the dot chain)
        float nR = 0.f, nZ = 0.f, nN = 0.f;
        int tn = t + 1;
        if (kq == 0 && tn < t1) {
            if (tn < len) {
                const unsigned* gp = gb2 + (size_t)(tn - t0) * 384;
                nR = unpk(gp[0], sel); nZ = unpk(gp[128], sel); nN = unpk(gp[256], sel);
            } else {
                nR = unpk(bias2[c >> 1], sel);
                nZ = unpk(bias2[128 + (c >> 1)], sel);
                nN = unpk(bias2[256 + (c >> 1)], sel);
            }
        }
        // 96 fdot2 over 8 wave-uniform h-quads
        float a00 = 0.f, a01 = 0.f, a10 = 0.f, a11 = 0.f, a20 = 0.f, a21 = 0.f;
        const u32x4* hb = (const u32x4*)hl + kq * 8;
#pragma unroll
        for (int q = 0; q < 8; ++q) {
            u32x4 hq = hb[q];
            a00 = fdot2u(hq.x, wq[q][0].x, a00);
            a10 = fdot2u(hq.x, wq[q][1].x, a10);
            a20 = fdot2u(hq.x, wq[q][2].x, a20);
            a01 = fdot2u(hq.y, wq[q][0].y, a01);
            a11 = fdot2u(hq.y, wq[q][1].y, a11);
            a21 = fdot2u(hq.y, wq[q][2].y, a21);
            a00 = fdot2u(hq.z, wq[q][0].z, a00);
            a10 = fdot2u(hq.z, wq[q][1].z, a10);
            a20 = fdot2u(hq.z, wq[q][2].z, a20);
            a01 = fdot2u(hq.w, wq[q][0].w, a01);
            a11 = fdot2u(hq.w, wq[q][1].w, a11);
            a21 = fdot2u(hq.w, wq[q][2].w, a21);
        }
        float s0 = a00 + a01, s1 = a10 + a11, s2 = a20 + a21;
        if (kq > 0) {
            pl[(kq - 1) * 3 + 0][c] = s0;
            pl[(kq - 1) * 3 + 1][c] = s1;
            pl[(kq - 1) * 3 + 2][c] = s2;
        }
        __syncthreads();   // partials ready; all hl reads done
        if (kq == 0) {
            float hr = s0 + pl[0][c] + pl[3][c] + pl[6][c];
            float hz = s1 + pl[1][c] + pl[4][c] + pl[7][c];
            float hn = s2 + pl[2][c] + pl[5][c] + pl[8][c];
            float r = sigmf(gR + hr);
            float z = sigmf(gZ + hz);
            float n = tanhff(gN + r * (hn + bhN));
            h = (1.0f - z) * n + z * h;
            float hp = __shfl_xor(h, 1, 64);
            if (!(c & 1)) hl[c >> 1] = packf16(h, hp);
            gR = nR; gZ = nZ; gN = nN;
        }
        __syncthreads();   // new h visible
    }
    if (kq == 0) h_state[b * DDIM + c] = h;
}

// ---------------- epilogue: saliency = ((1+h·src)·(mem·wcol)+bsum)/16 ----------------
__global__ __launch_bounds__(256) void k_epi(
    const float* __restrict__ memory, const float* __restrict__ src_vid,
    const float* __restrict__ h_state, const float* __restrict__ wcol,
    const float* __restrict__ bsum, float* __restrict__ out) {
    int wid = blockIdx.x * 4 + (threadIdx.x >> 6);
    int lane = threadIdx.x & 63;
    int b = wid >> 11;
    int t = wid & 2047;
    const float4* mp = (const float4*)(memory + ((size_t)b * T_SEQ + t) * DDIM);
    const float4* sp = (const float4*)(src_vid + ((size_t)b * T_SEQ + t) * DDIM);
    const float4* hp = (const float4*)(h_state + b * DDIM);
    const float4* wp = (const float4*)wcol;
    float4 m = mp[lane], s = sp[lane], hv = hp[lane], wc = wp[lane];
    float s1 = m.x * wc.x + m.y * wc.y + m.z * wc.z + m.w * wc.w;
    float s2 = hv.x * s.x + hv.y * s.y + hv.z * s.z + hv.w * s.w;
    for (int off = 32; off; off >>= 1) {
        s1 += __shfl_down(s1, off, 64);
        s2 += __shfl_down(s2, off, 64);
    }
    if (lane == 0) out[(size_t)b * T_SEQ + t] = ((1.0f + s2) * s1 + *bsum) * 0.0625f;
}

extern "C" void kernel_launch(void* const* d_in, const int* in_sizes, int n_in,
                              void* d_out, int out_size, void* d_ws, size_t ws_size,
                              hipStream_t stream) {
    const float* logits  = (const float*)d_in[0];
    const float* spans   = (const float*)d_in[1];
    const float* memory  = (const float*)d_in[2];
    const float* src_vid = (const float*)d_in[3];
    const float* W_ih    = (const float*)d_in[4];
    const float* W_hh    = (const float*)d_in[5];
    const float* b_ih    = (const float*)d_in[6];
    const float* b_hh    = (const float*)d_in[7];
    const float* W_sal   = (const float*)d_in[8];
    const float* b_sal   = (const float*)d_in[9];
    float* out = (float*)d_out;
    char* ws = (char*)d_ws;

    const size_t OFF_META  = 0;        // 128 ints
    const size_t OFF_WCOL  = 1024;     // 256 f32
    const size_t OFF_BSUM  = 2048;     // 1 f32
    const size_t OFF_BIASC = 2560;     // 768 f32
    const size_t OFF_BIASP = 5632;     // 384 u32
    const size_t OFF_H     = 8192;     // 64*256 f32
    const size_t OFF_W4    = 73728;    // 98304 u32
    const size_t OFF_WFI   = 466944;   // 98304 u32
    const size_t OFF_GI    = 860160;   // gi2 packed f16 pairs

    int* meta        = (int*)(ws + OFF_META);
    float* wcol      = (float*)(ws + OFF_WCOL);
    float* bsum      = (float*)(ws + OFF_BSUM);
    float* bias_comb = (float*)(ws + OFF_BIASC);
    unsigned* biasp  = (unsigned*)(ws + OFF_BIASP);
    float* h_state   = (float*)(ws + OFF_H);
    unsigned* w4     = (unsigned*)(ws + OFF_W4);
    unsigned* wfragI = (unsigned*)(ws + OFF_WFI);
    unsigned* gi2    = (unsigned*)(ws + OFF_GI);

    size_t gi_cap = (ws_size > OFF_GI) ? (ws_size - OFF_GI) : 0;
    long long tc_max = (long long)(gi_cap / ((size_t)NB * 384 * 4));
    int TC = (tc_max > T_SEQ) ? T_SEQ : (int)tc_max;
    if (TC < 16) TC = 16;

    k_prologue<<<dim3(1), dim3(256), 0, stream>>>(
        logits, spans, W_sal, b_sal, b_ih, b_hh, meta, wcol, bsum, bias_comb, biasp);
    k_prep<<<dim3(G3), dim3(256), 0, stream>>>(W_hh, w4);
    k_prepI<<<dim3(384), dim3(256), 0, stream>>>(W_ih, wfragI);
    for (int t0 = 0; t0 < T_SEQ; t0 += TC) {
        int tc = T_SEQ - t0; if (tc > TC) tc = TC;
        k_gemm<<<dim3((tc + 255) / 256, NB), dim3(512), 0, stream>>>(
            src_vid, wfragI, bias_comb, meta, gi2, t0, tc, TC);
        k_gru<<<dim3(NB), dim3(1024), 0, stream>>>(
            gi2, w4, biasp, b_hh, meta, h_state, t0, t0 + tc, TC);
    }
    k_epi<<<dim3(NB * T_SEQ / 4), dim3(256), 0, stream>>>(
        memory, src_vid, h_state, wcol, bsum, out);
}

// Round 16
// 2591.659 us; speedup vs baseline: 1.1544x; 1.1544x over previous
//
#include <hip/hip_runtime.h>
#include <hip/hip_bf16.h>
#include <stdint.h>

#define T_SEQ 2048
#define DDIM 256
#define G3 768
#define NB 64
#define NQR 10

typedef _Float16 h2f __attribute__((ext_vector_type(2)));
typedef _Float16 f16x8 __attribute__((ext_vector_type(8)));
typedef float f32x4 __attribute__((ext_vector_type(4)));
typedef unsigned u32x4 __attribute__((ext_vector_type(4)));

__device__ __forceinline__ float fdot2u(unsigned a, unsigned b, float c) {
    return __builtin_amdgcn_fdot2(__builtin_bit_cast(h2f, a),
                                  __builtin_bit_cast(h2f, b), c, false);
}
__device__ __forceinline__ unsigned packf16(float a, float b) {
    auto p = __builtin_amdgcn_cvt_pkrtz(a, b);   // __fp16 ext_vector(2)
    return __builtin_bit_cast(unsigned, p);
}
__device__ __forceinline__ float unpk(unsigned u, int hi) {
    h2f p = __builtin_bit_cast(h2f, u);
    return hi ? (float)p[1] : (float)p[0];
}
__device__ __forceinline__ float sigmf(float x) { return 1.0f / (1.0f + __expf(-x)); }
__device__ __forceinline__ float tanhff(float x) {
    float ax = fabsf(x);
    float e = __expf(2.0f * ax);
    float t = 1.0f - 2.0f / (e + 1.0f);
    return copysignf(t, x);
}

// ---------------- prologue: span selection + wcol + bsum + combined bias -------
// bias_comb[g] = b_ih[g] + (g<512 ? b_hh[g] : 0)   (b_hh r,z folded into gi)
__global__ __launch_bounds__(256) void k_prologue(
    const float* __restrict__ logits, const float* __restrict__ spans,
    const float* __restrict__ W_sal, const float* __restrict__ b_sal,
    const float* __restrict__ b_ih, const float* __restrict__ b_hh,
    int* __restrict__ meta, float* __restrict__ wcol, float* __restrict__ bsum,
    float* __restrict__ bias_comb) {
    int tid = threadIdx.x;
    if (tid < NB) {
        int b = tid;
        float bestv = -1e30f; int best = 0;
        for (int q = 0; q < NQR; ++q) {
            float l0 = logits[(b * NQR + q) * 2 + 0];
            float l1 = logits[(b * NQR + q) * 2 + 1];
            float sc = sigmf(l0 - l1);   // monotone in softmax[...,0]
            if (sc > bestv) { bestv = sc; best = q; }
        }
        float cx = spans[(b * NQR + best) * 2 + 0];
        float w  = spans[(b * NQR + best) * 2 + 1];
        float x0 = (cx - 0.5f * w) * (float)(T_SEQ * 2);
        float x1 = (cx + 0.5f * w) * (float)(T_SEQ * 2);
        int se0 = (int)floorf(x0 * 0.5f);
        int se1 = (int)floorf(x1 * 0.5f);
        int start = min(max(se0, 0), T_SEQ - 1);
        int end_eff = min(se1, T_SEQ - 1);
        int len = end_eff - start + 1;
        if (len < 0) len = 0;
        meta[b] = start; meta[NB + b] = len;
    }
    float acc = 0.f;
    for (int e = 0; e < DDIM; ++e) acc += W_sal[e * DDIM + tid];
    wcol[tid] = acc;
    if (tid < 64) {
        float p = b_sal[tid] + b_sal[tid + 64] + b_sal[tid + 128] + b_sal[tid + 192];
        for (int off = 32; off; off >>= 1) p += __shfl_down(p, off, 64);
        if (tid == 0) *bsum = p;
    }
#pragma unroll
    for (int r = 0; r < 3; ++r) {
        int g = tid + r * 256;
        bias_comb[g] = b_ih[g] + (g < 512 ? b_hh[g] : 0.f);
    }
}

// ---------------- prep: pack W_hh to u32x4 f16 quads (k_gru format) ----------
__global__ __launch_bounds__(256) void k_prep(
    const float* __restrict__ W_hh, unsigned* __restrict__ w4) {
    int g = blockIdx.x, k = threadIdx.x;
    if (k < 128) {  // k = pair index
        unsigned v = packf16(W_hh[g * DDIM + 2 * k], W_hh[g * DDIM + 2 * k + 1]);
        w4[((k >> 2) * G3 + g) * 4 + (k & 3)] = v;
    }
}

// ---------------- prepI: W_ih -> MFMA B-fragments (f16 packed) ----------------
__global__ __launch_bounds__(256) void k_prepI(
    const float* __restrict__ W_ih, unsigned* __restrict__ wfragI) {
    int u = blockIdx.x * 256 + threadIdx.x;     // 98304 total
    int jj = u & 3;
    int l  = (u >> 2) & 63;
    int kc = (u >> 8) & 7;
    int ct = u >> 11;
    int col = ct * 16 + (l & 15);
    int k = kc * 32 + ((l >> 4) << 3) + jj * 2;
    wfragI[u] = packf16(W_ih[col * DDIM + k], W_ih[col * DDIM + k + 1]);
}

// ---------------- gi GEMM (MFMA): gi2 = f16(sliced @ W_ih^T + bias_comb) ------
__global__ __launch_bounds__(512, 2) void k_gemm(
    const float* __restrict__ src_vid, const unsigned* __restrict__ wfragI,
    const float* __restrict__ bias_comb, const int* __restrict__ meta,
    unsigned* __restrict__ gi2, int t0, int tc, int TC) {
    int b = blockIdx.y;
    int len = meta[NB + b];
    int start = meta[b];
    int tbase = t0 + blockIdx.x * 256;
    int tend = t0 + tc; if (tend > len) tend = len;
    int tcap = tbase + 256; if (tend > tcap) tend = tcap;
    if (tbase >= tend) return;

    int tid = threadIdx.x, lane = tid & 63, w = tid >> 6;

    u32x4 bfr[6][8];
    const u32x4* wf = (const u32x4*)wfragI;
#pragma unroll
    for (int j = 0; j < 6; ++j)
#pragma unroll
        for (int kc = 0; kc < 8; ++kc)
            bfr[j][kc] = wf[((w * 6 + j) * 8 + kc) * 64 + lane];

    int row = lane & 15, kg = lane >> 4;
    float bv[6];
#pragma unroll
    for (int j = 0; j < 6; ++j) bv[j] = bias_comb[(w * 6 + j) * 16 + row];

    __shared__ unsigned As[2048];   // 16 rows x 128 pairs, swizzled
    int sr = tid >> 5, sx = tid & 31;

    for (int tch = tbase; tch < tend; tch += 16) {
        int tr = tch + sr;
        u32x4 pk = {0u, 0u, 0u, 0u};
        if (tr < len) {
            const float* sp = src_vid + ((size_t)b * T_SEQ + start + tr) * DDIM + sx * 8;
            float4 a0 = *(const float4*)sp;
            float4 a1 = *(const float4*)(sp + 4);
            pk[0] = packf16(a0.x, a0.y); pk[1] = packf16(a0.z, a0.w);
            pk[2] = packf16(a1.x, a1.y); pk[3] = packf16(a1.z, a1.w);
        }
        *(u32x4*)&As[sr * 128 + ((sx ^ sr) << 2)] = pk;
        __syncthreads();

        f32x4 d[6];
#pragma unroll
        for (int j = 0; j < 6; ++j) d[j] = (f32x4){bv[j], bv[j], bv[j], bv[j]};
#pragma unroll
        for (int kc = 0; kc < 8; ++kc) {
            u32x4 av = *(const u32x4*)&As[row * 128 + (((kc * 4 + kg) ^ row) << 2)];
            f16x8 af = __builtin_bit_cast(f16x8, av);
#pragma unroll
            for (int j = 0; j < 6; ++j)
                d[j] = __builtin_amdgcn_mfma_f32_16x16x32_f16(
                    af, __builtin_bit_cast(f16x8, bfr[j][kc]), d[j], 0, 0, 0);
        }

#pragma unroll
        for (int j = 0; j < 6; ++j) {
            int cflat = (w * 6 + j) * 16 + row;
            int gate = cflat >> 8;
            int pairi = (cflat & 255) >> 1;
#pragma unroll
            for (int reg = 0; reg < 4; ++reg) {
                int t = tch + kg * 4 + reg;
                float v = d[j][reg];
                float o = __shfl_xor(v, 1, 64);
                if (!(lane & 1) && t < tend)
                    gi2[((size_t)b * TC + (t - t0)) * 384 + gate * 128 + pairi] =
                        packf16(v, o);
            }
        }
        __syncthreads();
    }
}

// ---------------- GRU recurrence (R8 structure + micro-surgery) ----------------
// Changes vs R14: (1) h published via direct ds_write_b16 (no shfl+pack on the
// tanh->barrier critical path); (2) b_hh r,z folded into gi (bias_comb);
// (3) dot accumulators init 0.
__global__ void __launch_bounds__(512, 2) k_gru(
    const unsigned* __restrict__ gi2, const unsigned* __restrict__ w4,
    const float* __restrict__ bias_comb, const float* __restrict__ b_hh,
    const int* __restrict__ meta, float* __restrict__ h_state,
    int t0, int t1, int TC) {
    int b = blockIdx.x, tid = threadIdx.x;
    int c = tid & 255, half = tid >> 8;
    int len = meta[NB + b];

    u32x4 wrq[16], wzq[16], wnq[16];
    const u32x4* w4v = (const u32x4*)w4;
    const u32x4* wb = w4v + (size_t)(half * 16) * G3;
#pragma unroll
    for (int q = 0; q < 16; ++q) {
        wrq[q] = wb[q * G3 + c];
        wzq[q] = wb[q * G3 + 256 + c];
        wnq[q] = wb[q * G3 + 512 + c];
    }

    float bcR = bias_comb[c];            // b_ih + b_hh (r)
    float bcZ = bias_comb[256 + c];      // b_ih + b_hh (z)
    float bcN = bias_comb[512 + c];      // b_ih only (n)
    float bhN = b_hh[512 + c];

    __shared__ unsigned hl[128];         // packed f16 h (256 values)
    __shared__ float pl[3][256];

    _Float16* hlh = (_Float16*)hl;

    float h = 0.f;
    if (half == 0) {
        if (t0 != 0) h = h_state[b * DDIM + c];
        hlh[c] = (_Float16)h;            // direct b16 store, 2 lanes/bank = free
    }

    const unsigned* gb2 = gi2 + (size_t)b * TC * 384 + (c >> 1);
    int sel = c & 1;
    float gR = bcR, gZ = bcZ, gN = bcN;
    if (half == 0 && t0 < t1 && t0 < len) {
        gR = unpk(gb2[0], sel); gZ = unpk(gb2[128], sel); gN = unpk(gb2[256], sel);
    }
    __syncthreads();

    for (int t = t0; t < t1; ++t) {
        float nR = bcR, nZ = bcZ, nN = bcN;
        int tn = t + 1;
        if (half == 0 && tn < t1 && tn < len) {
            const unsigned* gp = gb2 + (size_t)(tn - t0) * 384;
            nR = unpk(gp[0], sel); nZ = unpk(gp[128], sel); nN = unpk(gp[256], sel);
        }
        float r0 = 0.f, z0 = 0.f, n0 = 0.f, r1 = 0.f, z1 = 0.f, n1 = 0.f;
        const u32x4* hb = (const u32x4*)hl + half * 16;
#pragma unroll
        for (int q = 0; q < 16; ++q) {
            u32x4 h4 = hb[q];
            r0 = fdot2u(h4.x, wrq[q].x, r0);
            z0 = fdot2u(h4.x, wzq[q].x, z0);
            n0 = fdot2u(h4.x, wnq[q].x, n0);
            r1 = fdot2u(h4.y, wrq[q].y, r1);
            z1 = fdot2u(h4.y, wzq[q].y, z1);
            n1 = fdot2u(h4.y, wnq[q].y, n1);
            r0 = fdot2u(h4.z, wrq[q].z, r0);
            z0 = fdot2u(h4.z, wzq[q].z, z0);
            n0 = fdot2u(h4.z, wnq[q].z, n0);
            r1 = fdot2u(h4.w, wrq[q].w, r1);
            z1 = fdot2u(h4.w, wzq[q].w, z1);
            n1 = fdot2u(h4.w, wnq[q].w, n1);
        }
        float hr = r0 + r1, hz = z0 + z1, hn = n0 + n1;
        if (half == 1) {
            pl[0][c] = hr; pl[1][c] = hz; pl[2][c] = hn;
        }
        __syncthreads();
        if (half == 0) {
            hr += pl[0][c]; hz += pl[1][c]; hn += pl[2][c];
            float r = sigmf(gR + hr);
            float z = sigmf(gZ + hz);
            float n = tanhff(gN + r * (hn + bhN));
            h = (1.0f - z) * n + z * h;
            hlh[c] = (_Float16)h;        // critical-path store, no shuffle
        }
        gR = nR; gZ = nZ; gN = nN;
        __syncthreads();
    }
    if (half == 0) h_state[b * DDIM + c] = h;
}

// ---------------- epilogue: saliency = ((1+h·src)·(mem·wcol)+bsum)/16 ----------------
__global__ __launch_bounds__(256) void k_epi(
    const float* __restrict__ memory, const float* __restrict__ src_vid,
    const float* __restrict__ h_state, const float* __restrict__ wcol,
    const float* __restrict__ bsum, float* __restrict__ out) {
    int wid = blockIdx.x * 4 + (threadIdx.x >> 6);
    int lane = threadIdx.x & 63;
    int b = wid >> 11;
    int t = wid & 2047;
    const float4* mp = (const float4*)(memory + ((size_t)b * T_SEQ + t) * DDIM);
    const float4* sp = (const float4*)(src_vid + ((size_t)b * T_SEQ + t) * DDIM);
    const float4* hp = (const float4*)(h_state + b * DDIM);
    const float4* wp = (const float4*)wcol;
    float4 m = mp[lane], s = sp[lane], hv = hp[lane], wc = wp[lane];
    float s1 = m.x * wc.x + m.y * wc.y + m.z * wc.z + m.w * wc.w;
    float s2 = hv.x * s.x + hv.y * s.y + hv.z * s.z + hv.w * s.w;
    for (int off = 32; off; off >>= 1) {
        s1 += __shfl_down(s1, off, 64);
        s2 += __shfl_down(s2, off, 64);
    }
    if (lane == 0) out[(size_t)b * T_SEQ + t] = ((1.0f + s2) * s1 + *bsum) * 0.0625f;
}

extern "C" void kernel_launch(void* const* d_in, const int* in_sizes, int n_in,
                              void* d_out, int out_size, void* d_ws, size_t ws_size,
                              hipStream_t stream) {
    const float* logits  = (const float*)d_in[0];
    const float* spans   = (const float*)d_in[1];
    const float* memory  = (const float*)d_in[2];
    const float* src_vid = (const float*)d_in[3];
    const float* W_ih    = (const float*)d_in[4];
    const float* W_hh    = (const float*)d_in[5];
    const float* b_ih    = (const float*)d_in[6];
    const float* b_hh    = (const float*)d_in[7];
    const float* W_sal   = (const float*)d_in[8];
    const float* b_sal   = (const float*)d_in[9];
    float* out = (float*)d_out;
    char* ws = (char*)d_ws;

    const size_t OFF_META  = 0;        // 128 ints
    const size_t OFF_WCOL  = 1024;     // 256 f32
    const size_t OFF_BSUM  = 2048;     // 1 f32
    const size_t OFF_BIASC = 2560;     // 768 f32
    const size_t OFF_H     = 8192;     // 64*256 f32
    const size_t OFF_W4    = 73728;    // 98304 u32
    const size_t OFF_WFI   = 466944;   // 98304 u32
    const size_t OFF_GI    = 860160;   // gi2 packed f16 pairs

    int* meta        = (int*)(ws + OFF_META);
    float* wcol      = (float*)(ws + OFF_WCOL);
    float* bsum      = (float*)(ws + OFF_BSUM);
    float* bias_comb = (float*)(ws + OFF_BIASC);
    float* h_state   = (float*)(ws + OFF_H);
    unsigned* w4     = (unsigned*)(ws + OFF_W4);
    unsigned* wfragI = (unsigned*)(ws + OFF_WFI);
    unsigned* gi2    = (unsigned*)(ws + OFF_GI);

    size_t gi_cap = (ws_size > OFF_GI) ? (ws_size - OFF_GI) : 0;
    long long tc_max = (long long)(gi_cap / ((size_t)NB * 384 * 4));
    int TC = (tc_max > T_SEQ) ? T_SEQ : (int)tc_max;
    if (TC < 16) TC = 16;

    k_prologue<<<dim3(1), dim3(256), 0, stream>>>(
        logits, spans, W_sal, b_sal, b_ih, b_hh, meta, wcol, bsum, bias_comb);
    k_prep<<<dim3(G3), dim3(256), 0, stream>>>(W_hh, w4);
    k_prepI<<<dim3(384), dim3(256), 0, stream>>>(W_ih, wfragI);
    for (int t0 = 0; t0 < T_SEQ; t0 += TC) {
        int tc = T_SEQ - t0; if (tc > TC) tc = TC;
        k_gemm<<<dim3((tc + 255) / 256, NB), dim3(512), 0, stream>>>(
            src_vid, wfragI, bias_comb, meta, gi2, t0, tc, TC);
        k_gru<<<dim3(NB), dim3(512), 0, stream>>>(
            gi2, w4, bias_comb, b_hh, meta, h_state, t0, t0 + tc, TC);
    }
    k_epi<<<dim3(NB * T_SEQ / 4), dim3(256), 0, stream>>>(
        memory, src_vid, h_state, wcol, bsum, out);
}